// Round 3
// baseline (592.086 us; speedup 1.0000x reference)
//
#include <hip/hip_runtime.h>

// out[b, k] = x[b, ii[k]] * x[b, jj[k]] for (ii, jj) = triu_indices(512).
// B=1024, D=512, K=D*(D+1)/2=131328. Output 538 MB fp32 -> write-BW-bound.
// Roofline: ~540 MB HBM traffic / 6.3 TB/s achievable ~= 86 us.

#define DD 512
#define KK 131328   // DD*(DD+1)/2, divisible by 4
#define K4 (KK / 4) // 32832

// Native clang vector type: __builtin_nontemporal_store requires this
// (HIP_vector_type float4 is rejected -- round 2 compile error).
typedef float f32x4 __attribute__((ext_vector_type(4)));

__device__ __forceinline__ int off_row(int i) {
    // number of pairs before row i: i*DD - i*(i-1)/2 = i*(2*DD+1-i)/2
    return (i * (2 * DD + 1 - i)) >> 1;
}

__global__ void __launch_bounds__(256)
descartes_ext_kernel(const float* __restrict__ x, float* __restrict__ out, int total4) {
    for (int g = blockIdx.x * blockDim.x + threadIdx.x; g < total4;
         g += gridDim.x * blockDim.x) {
        const int b = g / K4;            // magic-mul division by constant
        const int r = g - b * K4;
        const int k = r * 4;

        // Invert triangular index: largest i with off_row(i) <= k.
        // disc = (2D+1)^2 - 8k = 1050625 - 8k; both terms < 2^24 -> exact fp32.
        const float disc = (float)(1050625 - 8 * k);
        int i = (int)((1025.0f - sqrtf(disc)) * 0.5f);
        // sqrt is <=1 ulp off -> i estimate is off by at most one step.
        i += (off_row(i + 1) <= k);      // branch-free fixup up
        i -= (off_row(i) > k);           // branch-free fixup down
        int j = k - off_row(i) + i;

        const float* __restrict__ xr = x + b * DD;
        float xi = xr[i];
        f32x4 o;
        o.x = xi * xr[j];
        if (++j >= DD) { ++i; j = i; xi = xr[i]; }
        o.y = xi * xr[j];
        if (++j >= DD) { ++i; j = i; xi = xr[i]; }
        o.z = xi * xr[j];
        if (++j >= DD) { ++i; j = i; xi = xr[i]; }
        o.w = xi * xr[j];

        // Streaming output, never re-read: non-temporal store (nt flag).
        __builtin_nontemporal_store(o, reinterpret_cast<f32x4*>(out + (size_t)g * 4));
    }
}

extern "C" void kernel_launch(void* const* d_in, const int* in_sizes, int n_in,
                              void* d_out, int out_size, void* d_ws, size_t ws_size,
                              hipStream_t stream) {
    const float* x = (const float*)d_in[0];
    float* out = (float*)d_out;

    const int Bn = in_sizes[0] / DD;       // 1024 for the reference shape
    const int total4 = Bn * K4;            // 33,619,968 float4 stores

    const int block = 256;
    const int grid = 2048;                 // memory-bound cap; grid-stride the rest
    descartes_ext_kernel<<<grid, block, 0, stream>>>(x, out, total4);
}